// Round 3
// baseline (459.750 us; speedup 1.0000x reference)
//
#include <hip/hip_runtime.h>
#include <hip/hip_bf16.h>

#define DD 64
#define NEG_SLOPE 0.2f
#define HS 68          // padded LDS stride for h tile
#define CAP 128        // per-node alpha/col LDS cache (deg is Poisson(16); 128 is >>max)
#define BSH 5          // bucket = dst >> 5 (32 nodes per bucket)
#define PACK_BITS 27   // packed ebuf entry: (dstLocal<<27) | src   (needs N < 2^27)

// ---------------------------------------------------------------------------
// Fused: h = relu(x@W0 + b0); hx = h@W1; sarr/darr = hx.a_src / hx.a_dst
// 64-node tile; thread = (ng,fg) holds 4 nodes x 4 features
// ---------------------------------------------------------------------------
__global__ __launch_bounds__(256) void mm_fused(
    const float* __restrict__ x,
    const float* __restrict__ W0, const float* __restrict__ b0,
    const float* __restrict__ W1,
    const float* __restrict__ a_src, const float* __restrict__ a_dst,
    float* __restrict__ h, float* __restrict__ hx,
    float* __restrict__ sarr, float* __restrict__ darr, int n)
{
    __shared__ float Wsh[DD * DD];
    __shared__ float Hsh[DD * HS];
    int tid = threadIdx.x;
    for (int i = tid * 4; i < DD * DD; i += 1024)
        *(float4*)&Wsh[i] = *(const float4*)&W0[i];

    int fg = tid & 15, ng = tid >> 4;
    int tile0 = blockIdx.x * 64;
    for (int p = 0; p < 4; ++p) {
        int nl = p * 16 + ng, gn = tile0 + nl;
        if (gn < n)
            *(float4*)&Hsh[nl * HS + 4 * fg] = *(const float4*)&x[gn * DD + 4 * fg];
    }
    __syncthreads();

    float4 acc[4];
#pragma unroll
    for (int j = 0; j < 4; ++j) acc[j] = float4{0.f, 0.f, 0.f, 0.f};
#pragma unroll 8
    for (int k = 0; k < DD; ++k) {
        float4 w4 = *(float4*)&Wsh[k * DD + 4 * fg];
#pragma unroll
        for (int j = 0; j < 4; ++j) {
            float hv = Hsh[(4 * ng + j) * HS + k];
            acc[j].x += hv * w4.x; acc[j].y += hv * w4.y;
            acc[j].z += hv * w4.z; acc[j].w += hv * w4.w;
        }
    }

    float4 b4 = *(const float4*)&b0[4 * fg];
    float4 o[4];
#pragma unroll
    for (int j = 0; j < 4; ++j) {
        o[j].x = fmaxf(acc[j].x + b4.x, 0.f);
        o[j].y = fmaxf(acc[j].y + b4.y, 0.f);
        o[j].z = fmaxf(acc[j].z + b4.z, 0.f);
        o[j].w = fmaxf(acc[j].w + b4.w, 0.f);
        int gn = tile0 + 4 * ng + j;
        if (gn < n) *(float4*)&h[gn * DD + 4 * fg] = o[j];
    }
    __syncthreads();   // everyone done reading Wsh(W0)/Hsh(x)

    // restage: Hsh <- h tile, Wsh <- W1
#pragma unroll
    for (int j = 0; j < 4; ++j)
        *(float4*)&Hsh[(4 * ng + j) * HS + 4 * fg] = o[j];
    for (int i = tid * 4; i < DD * DD; i += 1024)
        *(float4*)&Wsh[i] = *(const float4*)&W1[i];
    __syncthreads();

#pragma unroll
    for (int j = 0; j < 4; ++j) acc[j] = float4{0.f, 0.f, 0.f, 0.f};
#pragma unroll 8
    for (int k = 0; k < DD; ++k) {
        float4 w4 = *(float4*)&Wsh[k * DD + 4 * fg];
#pragma unroll
        for (int j = 0; j < 4; ++j) {
            float hv = Hsh[(4 * ng + j) * HS + k];
            acc[j].x += hv * w4.x; acc[j].y += hv * w4.y;
            acc[j].z += hv * w4.z; acc[j].w += hv * w4.w;
        }
    }

    float4 as4 = *(const float4*)&a_src[4 * fg];
    float4 ad4 = *(const float4*)&a_dst[4 * fg];
#pragma unroll
    for (int j = 0; j < 4; ++j) {
        int gn = tile0 + 4 * ng + j;
        if (gn < n) *(float4*)&hx[gn * DD + 4 * fg] = acc[j];
        float ps = acc[j].x * as4.x + acc[j].y * as4.y + acc[j].z * as4.z + acc[j].w * as4.w;
        float pd = acc[j].x * ad4.x + acc[j].y * ad4.y + acc[j].z * ad4.z + acc[j].w * ad4.w;
#pragma unroll
        for (int off = 8; off; off >>= 1) {
            ps += __shfl_xor(ps, off);
            pd += __shfl_xor(pd, off);
        }
        if (fg == 0 && gn < n) { sarr[gn] = ps; darr[gn] = pd; }
    }
}

// ---------------------------------------------------------------------------
// Plain GAT matmul for layer 2 (input h already in global)
// ---------------------------------------------------------------------------
__global__ __launch_bounds__(256) void mm_gat(
    const float* __restrict__ h, const float* __restrict__ W,
    const float* __restrict__ a_src, const float* __restrict__ a_dst,
    float* __restrict__ hx, float* __restrict__ sarr, float* __restrict__ darr,
    int n)
{
    __shared__ float Wsh[DD * DD];
    __shared__ float Hsh[DD * HS];
    int tid = threadIdx.x;
    for (int i = tid * 4; i < DD * DD; i += 1024)
        *(float4*)&Wsh[i] = *(const float4*)&W[i];

    int fg = tid & 15, ng = tid >> 4;
    int tile0 = blockIdx.x * 64;
    for (int p = 0; p < 4; ++p) {
        int nl = p * 16 + ng, gn = tile0 + nl;
        if (gn < n)
            *(float4*)&Hsh[nl * HS + 4 * fg] = *(const float4*)&h[gn * DD + 4 * fg];
    }
    __syncthreads();

    float4 acc[4];
#pragma unroll
    for (int j = 0; j < 4; ++j) acc[j] = float4{0.f, 0.f, 0.f, 0.f};
#pragma unroll 8
    for (int k = 0; k < DD; ++k) {
        float4 w4 = *(float4*)&Wsh[k * DD + 4 * fg];
#pragma unroll
        for (int j = 0; j < 4; ++j) {
            float hv = Hsh[(4 * ng + j) * HS + k];
            acc[j].x += hv * w4.x; acc[j].y += hv * w4.y;
            acc[j].z += hv * w4.z; acc[j].w += hv * w4.w;
        }
    }

    float4 as4 = *(const float4*)&a_src[4 * fg];
    float4 ad4 = *(const float4*)&a_dst[4 * fg];
#pragma unroll
    for (int j = 0; j < 4; ++j) {
        int gn = tile0 + 4 * ng + j;
        if (gn < n) *(float4*)&hx[gn * DD + 4 * fg] = acc[j];
        float ps = acc[j].x * as4.x + acc[j].y * as4.y + acc[j].z * as4.z + acc[j].w * as4.w;
        float pd = acc[j].x * ad4.x + acc[j].y * ad4.y + acc[j].z * ad4.z + acc[j].w * ad4.w;
#pragma unroll
        for (int off = 8; off; off >>= 1) {
            ps += __shfl_xor(ps, off);
            pd += __shfl_xor(pd, off);
        }
        if (fg == 0 && gn < n) { sarr[gn] = ps; darr[gn] = pd; }
    }
}

// ---------------------------------------------------------------------------
// Bucketed CSR build
// ---------------------------------------------------------------------------
__global__ void bcount_kernel(const int* __restrict__ dst, int* __restrict__ bcnt, int E)
{
    int e = blockIdx.x * 256 + threadIdx.x;
    if (e < E) atomicAdd(&bcnt[dst[e] >> BSH], 1);
}

__device__ __forceinline__ int wave_incl_scan(int v, int lane)
{
#pragma unroll
    for (int off = 1; off < 64; off <<= 1) {
        int t = __shfl_up(v, off);
        if (lane >= off) v += t;
    }
    return v;
}

// single block: exclusive scan of bcnt[0..NB) -> boff, bcur; boff[NB]=E; row_ptr[N]=E
__global__ __launch_bounds__(256) void bscan_kernel(
    const int* __restrict__ bcnt, int* __restrict__ boff, int* __restrict__ bcur,
    int* __restrict__ row_ptr, int NB, int N, int E)
{
    __shared__ int tsum[256];
    __shared__ int wsum[4];
    int tid = threadIdx.x;
    int base = tid * 8;
    int loc[8];
    int sum = 0;
#pragma unroll
    for (int i = 0; i < 8; ++i) {
        int idx = base + i;
        int v = (idx < NB) ? bcnt[idx] : 0;
        loc[i] = sum; sum += v;
    }
    tsum[tid] = sum;
    __syncthreads();
    int lane = tid & 63, w = tid >> 6;
    int v = tsum[tid];
    int incl = wave_incl_scan(v, lane);
    if (lane == 63) wsum[w] = incl;
    __syncthreads();
    int wo = 0;
    for (int i = 0; i < w; ++i) wo += wsum[i];
    int texcl = wo + incl - v;
#pragma unroll
    for (int i = 0; i < 8; ++i) {
        int idx = base + i;
        if (idx < NB) { int o = texcl + loc[i]; boff[idx] = o; bcur[idx] = o; }
    }
    if (tid == 255) { boff[NB] = texcl + sum; row_ptr[N] = E; }
}

// scatter packed (dstLocal<<27)|src into bucket-clustered ebuf
__global__ void bscatter_kernel(const int* __restrict__ src, const int* __restrict__ dst,
                                int* __restrict__ bcur, int* __restrict__ ebuf, int E)
{
    int e = blockIdx.x * 256 + threadIdx.x;
    if (e < E) {
        int d = dst[e];
        int b = d >> BSH;
        int pos = atomicAdd(&bcur[b], 1);
        ebuf[pos] = src[e] | (int)(((unsigned)(d & 31)) << PACK_BITS);
    }
}

// one block per bucket: LDS hist(32) -> local scan -> row_ptr + clustered col
__global__ __launch_bounds__(256) void build_csr(
    const int* __restrict__ ebuf, const int* __restrict__ boff,
    int* __restrict__ row_ptr, int* __restrict__ col, int N)
{
    __shared__ int lcnt[32];
    __shared__ int loff[32];
    __shared__ int lcur[32];
    int b = blockIdx.x, tid = threadIdx.x;
    int e0 = boff[b], e1 = boff[b + 1];
    if (tid < 32) { lcnt[tid] = 0; lcur[tid] = 0; }
    __syncthreads();
    for (int e = e0 + tid; e < e1; e += 256) {
        int dl = ((unsigned)ebuf[e]) >> PACK_BITS;
        atomicAdd(&lcnt[dl], 1);
    }
    __syncthreads();
    if (tid == 0) {
        int a = 0;
        for (int i = 0; i < 32; ++i) { loff[i] = a; a += lcnt[i]; }
    }
    __syncthreads();
    if (tid < 32) {
        int node = b * 32 + tid;
        if (node < N) row_ptr[node] = e0 + loff[tid];
    }
    for (int e = e0 + tid; e < e1; e += 256) {
        int p = ebuf[e];
        int dl = ((unsigned)p) >> PACK_BITS;
        int s = p & ((1 << PACK_BITS) - 1);
        int r = atomicAdd(&lcur[dl], 1);
        col[e0 + loff[dl] + r] = s;
    }
}

// ---------------------------------------------------------------------------
// Softmax aggregation + relu + residual. Wave per node:
// 64 lanes = 4 edge-slots (es) x 16 feature-groups (fg, float4)
// ---------------------------------------------------------------------------
__global__ __launch_bounds__(256) void aggregate(
    const float4* __restrict__ hx4, const int* __restrict__ row_ptr,
    const int* __restrict__ col, const float* __restrict__ sarr,
    const float* __restrict__ darr, const float* __restrict__ bias,
    float* __restrict__ h, int n)
{
    __shared__ float aw[4][CAP];
    __shared__ int   ac[4][CAP];
    int tid = threadIdx.x;
    int wid = tid >> 6, lane = tid & 63, fg = lane & 15, es = lane >> 4;
    int v = blockIdx.x * 4 + wid;
    if (v >= n) return;

    int beg = row_ptr[v], end = row_ptr[v + 1];
    int deg = end - beg;
    float adi = darr[v];
    float m = -3.4e38f, s = 0.f;
    float4 acc = float4{0.f, 0.f, 0.f, 0.f};

    if (deg <= CAP) {
        for (int e = beg + lane; e < end; e += 64) {
            int c = col[e];
            float a = sarr[c] + adi;
            a = a > 0.f ? a : NEG_SLOPE * a;
            ac[wid][e - beg] = c;
            aw[wid][e - beg] = a;
            m = fmaxf(m, a);
        }
#pragma unroll
        for (int off = 32; off; off >>= 1) m = fmaxf(m, __shfl_xor(m, off));
        for (int i = lane; i < deg; i += 64) {
            float w = __expf(aw[wid][i] - m);
            aw[wid][i] = w; s += w;
        }
#pragma unroll
        for (int off = 32; off; off >>= 1) s += __shfl_xor(s, off);
#pragma unroll 2
        for (int i = es; i < deg; i += 4) {
            int c = ac[wid][i];
            float w = aw[wid][i];
            float4 hv = hx4[c * 16 + fg];
            acc.x += w * hv.x; acc.y += w * hv.y;
            acc.z += w * hv.z; acc.w += w * hv.w;
        }
    } else {
        // recompute fallback (deg > CAP; effectively never for this graph)
        for (int e = beg + lane; e < end; e += 64) {
            float a = sarr[col[e]] + adi;
            a = a > 0.f ? a : NEG_SLOPE * a;
            m = fmaxf(m, a);
        }
#pragma unroll
        for (int off = 32; off; off >>= 1) m = fmaxf(m, __shfl_xor(m, off));
        for (int e = beg + lane; e < end; e += 64) {
            float a = sarr[col[e]] + adi;
            a = a > 0.f ? a : NEG_SLOPE * a;
            s += __expf(a - m);
        }
#pragma unroll
        for (int off = 32; off; off >>= 1) s += __shfl_xor(s, off);
        for (int e = beg + es; e < end; e += 4) {
            int c = col[e];
            float a = sarr[c] + adi;
            a = a > 0.f ? a : NEG_SLOPE * a;
            float w = __expf(a - m);
            float4 hv = hx4[c * 16 + fg];
            acc.x += w * hv.x; acc.y += w * hv.y;
            acc.z += w * hv.z; acc.w += w * hv.w;
        }
    }

    // reduce across the 4 edge-slots (lanes differing in bits 4,5)
    acc.x += __shfl_xor(acc.x, 16); acc.y += __shfl_xor(acc.y, 16);
    acc.z += __shfl_xor(acc.z, 16); acc.w += __shfl_xor(acc.w, 16);
    acc.x += __shfl_xor(acc.x, 32); acc.y += __shfl_xor(acc.y, 32);
    acc.z += __shfl_xor(acc.z, 32); acc.w += __shfl_xor(acc.w, 32);

    if (es == 0) {
        float inv = (s > 0.f) ? 1.f / s : 0.f;
        float4 b4 = ((const float4*)bias)[fg];
        float4 o;
        o.x = fmaxf(acc.x * inv + b4.x, 0.f);
        o.y = fmaxf(acc.y * inv + b4.y, 0.f);
        o.z = fmaxf(acc.z * inv + b4.z, 0.f);
        o.w = fmaxf(acc.w * inv + b4.w, 0.f);
        float4* hp = (float4*)&h[v * DD + 4 * fg];
        float4 cur = *hp;
        cur.x += o.x; cur.y += o.y; cur.z += o.z; cur.w += o.w;
        *hp = cur;
    }
}

// ---------------------------------------------------------------------------
extern "C" void kernel_launch(void* const* d_in, const int* in_sizes, int n_in,
                              void* d_out, int out_size, void* d_ws, size_t ws_size,
                              hipStream_t stream)
{
    const float* x  = (const float*)d_in[0];
    const int*   ei = (const int*)d_in[1];
    const float* W0 = (const float*)d_in[4];
    const float* b0 = (const float*)d_in[5];
    const float* W1 = (const float*)d_in[6];
    const float* as1= (const float*)d_in[7];
    const float* ad1= (const float*)d_in[8];
    const float* b1 = (const float*)d_in[9];
    const float* W2 = (const float*)d_in[10];
    const float* as2= (const float*)d_in[11];
    const float* ad2= (const float*)d_in[12];
    const float* b2 = (const float*)d_in[13];

    int N = in_sizes[0] / DD;
    int E = in_sizes[1] / 2;
    int NB = (N + 31) >> BSH;
    float* h = (float*)d_out;

    // workspace layout (~20 MB)
    float* hx     = (float*)d_ws;              // N*64
    float* sarr   = hx + (size_t)N * DD;       // N
    float* darr   = sarr + N;                  // N
    int*   row_ptr= (int*)(darr + N);          // N+1
    int*   bcnt   = row_ptr + (N + 1);         // NB
    int*   boff   = bcnt + NB;                 // NB+1
    int*   bcur   = boff + (NB + 1);           // NB
    int*   ebuf   = bcur + NB;                 // E
    int*   colb   = ebuf + E;                  // E

    const int* src = ei;
    const int* dst = ei + E;

    int eblocks  = (E + 255) / 256;
    int mm_tiles = (N + 63) / 64;
    int agg_blks = (N + 3) / 4;

    // ---- bucketed CSR build ----
    hipMemsetAsync(bcnt, 0, (size_t)NB * sizeof(int), stream);
    bcount_kernel<<<eblocks, 256, 0, stream>>>(dst, bcnt, E);
    bscan_kernel<<<1, 256, 0, stream>>>(bcnt, boff, bcur, row_ptr, NB, N, E);
    bscatter_kernel<<<eblocks, 256, 0, stream>>>(src, dst, bcur, ebuf, E);
    build_csr<<<NB, 256, 0, stream>>>(ebuf, boff, row_ptr, colb, N);

    // ---- layer 0 + GAT-1 matmul (fused) ----
    mm_fused<<<mm_tiles, 256, 0, stream>>>(x, W0, b0, W1, as1, ad1, h, hx, sarr, darr, N);
    aggregate<<<agg_blks, 256, 0, stream>>>((const float4*)hx, row_ptr, colb, sarr, darr, b1, h, N);

    // ---- GAT layer 2 ----
    mm_gat<<<mm_tiles, 256, 0, stream>>>(h, W2, as2, ad2, hx, sarr, darr, N);
    aggregate<<<agg_blks, 256, 0, stream>>>((const float4*)hx, row_ptr, colb, sarr, darr, b2, h, N);
}

// Round 4
// 402.705 us; speedup vs baseline: 1.1417x; 1.1417x over previous
//
#include <hip/hip_runtime.h>
#include <hip/hip_bf16.h>

#define DD 64
#define NEG_SLOPE 0.2f
#define HS 68          // padded LDS stride for h tile
#define CAP 128        // per-node alpha/col LDS cache in aggregate
#define BSH 8          // bucket = dst >> 8 (256 nodes per bucket)
#define BN  256        // nodes per bucket
#define STAGE_CAP 6144 // LDS col staging per bucket (expected ~4082 edges)

// ---------------------------------------------------------------------------
// Fused: h = relu(x@W0 + b0); hx = h@W1; sarr/darr = hx.a_src / hx.a_dst
// ---------------------------------------------------------------------------
__global__ __launch_bounds__(256) void mm_fused(
    const float* __restrict__ x,
    const float* __restrict__ W0, const float* __restrict__ b0,
    const float* __restrict__ W1,
    const float* __restrict__ a_src, const float* __restrict__ a_dst,
    float* __restrict__ h, float* __restrict__ hx,
    float* __restrict__ sarr, float* __restrict__ darr, int n)
{
    __shared__ float Wsh[DD * DD];
    __shared__ float Hsh[DD * HS];
    int tid = threadIdx.x;
    for (int i = tid * 4; i < DD * DD; i += 1024)
        *(float4*)&Wsh[i] = *(const float4*)&W0[i];

    int fg = tid & 15, ng = tid >> 4;
    int tile0 = blockIdx.x * 64;
    for (int p = 0; p < 4; ++p) {
        int nl = p * 16 + ng, gn = tile0 + nl;
        if (gn < n)
            *(float4*)&Hsh[nl * HS + 4 * fg] = *(const float4*)&x[gn * DD + 4 * fg];
    }
    __syncthreads();

    float4 acc[4];
#pragma unroll
    for (int j = 0; j < 4; ++j) acc[j] = float4{0.f, 0.f, 0.f, 0.f};
#pragma unroll 8
    for (int k = 0; k < DD; ++k) {
        float4 w4 = *(float4*)&Wsh[k * DD + 4 * fg];
#pragma unroll
        for (int j = 0; j < 4; ++j) {
            float hv = Hsh[(4 * ng + j) * HS + k];
            acc[j].x += hv * w4.x; acc[j].y += hv * w4.y;
            acc[j].z += hv * w4.z; acc[j].w += hv * w4.w;
        }
    }

    float4 b4 = *(const float4*)&b0[4 * fg];
    float4 o[4];
#pragma unroll
    for (int j = 0; j < 4; ++j) {
        o[j].x = fmaxf(acc[j].x + b4.x, 0.f);
        o[j].y = fmaxf(acc[j].y + b4.y, 0.f);
        o[j].z = fmaxf(acc[j].z + b4.z, 0.f);
        o[j].w = fmaxf(acc[j].w + b4.w, 0.f);
        int gn = tile0 + 4 * ng + j;
        if (gn < n) *(float4*)&h[gn * DD + 4 * fg] = o[j];
    }
    __syncthreads();

#pragma unroll
    for (int j = 0; j < 4; ++j)
        *(float4*)&Hsh[(4 * ng + j) * HS + 4 * fg] = o[j];
    for (int i = tid * 4; i < DD * DD; i += 1024)
        *(float4*)&Wsh[i] = *(const float4*)&W1[i];
    __syncthreads();

#pragma unroll
    for (int j = 0; j < 4; ++j) acc[j] = float4{0.f, 0.f, 0.f, 0.f};
#pragma unroll 8
    for (int k = 0; k < DD; ++k) {
        float4 w4 = *(float4*)&Wsh[k * DD + 4 * fg];
#pragma unroll
        for (int j = 0; j < 4; ++j) {
            float hv = Hsh[(4 * ng + j) * HS + k];
            acc[j].x += hv * w4.x; acc[j].y += hv * w4.y;
            acc[j].z += hv * w4.z; acc[j].w += hv * w4.w;
        }
    }

    float4 as4 = *(const float4*)&a_src[4 * fg];
    float4 ad4 = *(const float4*)&a_dst[4 * fg];
#pragma unroll
    for (int j = 0; j < 4; ++j) {
        int gn = tile0 + 4 * ng + j;
        if (gn < n) *(float4*)&hx[gn * DD + 4 * fg] = acc[j];
        float ps = acc[j].x * as4.x + acc[j].y * as4.y + acc[j].z * as4.z + acc[j].w * as4.w;
        float pd = acc[j].x * ad4.x + acc[j].y * ad4.y + acc[j].z * ad4.z + acc[j].w * ad4.w;
#pragma unroll
        for (int off = 8; off; off >>= 1) {
            ps += __shfl_xor(ps, off);
            pd += __shfl_xor(pd, off);
        }
        if (fg == 0 && gn < n) { sarr[gn] = ps; darr[gn] = pd; }
    }
}

// ---------------------------------------------------------------------------
// Plain GAT matmul (layer 2)
// ---------------------------------------------------------------------------
__global__ __launch_bounds__(256) void mm_gat(
    const float* __restrict__ h, const float* __restrict__ W,
    const float* __restrict__ a_src, const float* __restrict__ a_dst,
    float* __restrict__ hx, float* __restrict__ sarr, float* __restrict__ darr,
    int n)
{
    __shared__ float Wsh[DD * DD];
    __shared__ float Hsh[DD * HS];
    int tid = threadIdx.x;
    for (int i = tid * 4; i < DD * DD; i += 1024)
        *(float4*)&Wsh[i] = *(const float4*)&W[i];

    int fg = tid & 15, ng = tid >> 4;
    int tile0 = blockIdx.x * 64;
    for (int p = 0; p < 4; ++p) {
        int nl = p * 16 + ng, gn = tile0 + nl;
        if (gn < n)
            *(float4*)&Hsh[nl * HS + 4 * fg] = *(const float4*)&h[gn * DD + 4 * fg];
    }
    __syncthreads();

    float4 acc[4];
#pragma unroll
    for (int j = 0; j < 4; ++j) acc[j] = float4{0.f, 0.f, 0.f, 0.f};
#pragma unroll 8
    for (int k = 0; k < DD; ++k) {
        float4 w4 = *(float4*)&Wsh[k * DD + 4 * fg];
#pragma unroll
        for (int j = 0; j < 4; ++j) {
            float hv = Hsh[(4 * ng + j) * HS + k];
            acc[j].x += hv * w4.x; acc[j].y += hv * w4.y;
            acc[j].z += hv * w4.z; acc[j].w += hv * w4.w;
        }
    }

    float4 as4 = *(const float4*)&a_src[4 * fg];
    float4 ad4 = *(const float4*)&a_dst[4 * fg];
#pragma unroll
    for (int j = 0; j < 4; ++j) {
        int gn = tile0 + 4 * ng + j;
        if (gn < n) *(float4*)&hx[gn * DD + 4 * fg] = acc[j];
        float ps = acc[j].x * as4.x + acc[j].y * as4.y + acc[j].z * as4.z + acc[j].w * as4.w;
        float pd = acc[j].x * ad4.x + acc[j].y * ad4.y + acc[j].z * ad4.z + acc[j].w * ad4.w;
#pragma unroll
        for (int off = 8; off; off >>= 1) {
            ps += __shfl_xor(ps, off);
            pd += __shfl_xor(pd, off);
        }
        if (fg == 0 && gn < n) { sarr[gn] = ps; darr[gn] = pd; }
    }
}

// ---------------------------------------------------------------------------
// CSR build, atomic-free (globally): each bucket block scans all of dst.
// ---------------------------------------------------------------------------
__device__ __forceinline__ int wave_incl_scan(int v, int lane)
{
#pragma unroll
    for (int off = 1; off < 64; off <<= 1) {
        int t = __shfl_up(v, off);
        if (lane >= off) v += t;
    }
    return v;
}

// A: per-bucket node counts (LDS hist) + bucket total. No global atomics.
__global__ __launch_bounds__(1024) void bucket_count(
    const int4* __restrict__ dst4, int* __restrict__ cnt,
    int* __restrict__ btot, int N, int E4)
{
    __shared__ int lcnt[BN];
    __shared__ int wred[16];
    int b = blockIdx.x, tid = threadIdx.x;
    if (tid < BN) lcnt[tid] = 0;
    __syncthreads();
    for (int i = tid; i < E4; i += 1024) {
        int4 d = dst4[i];
        if ((d.x >> BSH) == b) atomicAdd(&lcnt[d.x & (BN - 1)], 1);
        if ((d.y >> BSH) == b) atomicAdd(&lcnt[d.y & (BN - 1)], 1);
        if ((d.z >> BSH) == b) atomicAdd(&lcnt[d.z & (BN - 1)], 1);
        if ((d.w >> BSH) == b) atomicAdd(&lcnt[d.w & (BN - 1)], 1);
    }
    __syncthreads();
    int lane = tid & 63, w = tid >> 6;
    if (tid < BN) {
        int node = b * BN + tid;
        int v = lcnt[tid];
        if (node < N) cnt[node] = v;
        else v = 0;
#pragma unroll
        for (int off = 32; off; off >>= 1) v += __shfl_xor(v, off);
        if (lane == 0) wred[w] = v;
    }
    __syncthreads();
    if (tid == 0) btot[b] = wred[0] + wred[1] + wred[2] + wred[3];
}

// B: exclusive scan of bucket totals (single small block)
__global__ __launch_bounds__(256) void bucket_scan(
    const int* __restrict__ btot, int* __restrict__ boff,
    int* __restrict__ row_ptr, int NB, int N, int E)
{
    __shared__ int wsum[4];
    int tid = threadIdx.x, lane = tid & 63, w = tid >> 6;
    int v = (tid < NB) ? btot[tid] : 0;
    int incl = wave_incl_scan(v, lane);
    if (lane == 63) wsum[w] = incl;
    __syncthreads();
    int wo = 0;
    for (int i = 0; i < w; ++i) wo += wsum[i];
    if (tid < NB) boff[tid] = wo + incl - v;
    if (tid == 0) { boff[NB] = E; row_ptr[N] = E; }
}

// C: per-bucket: local scan of node counts -> row_ptr; re-scan dst, gather
//    src, rank via LDS cursors, stage col in LDS, flush contiguously.
__global__ __launch_bounds__(1024) void bucket_build(
    const int4* __restrict__ dst4, const int* __restrict__ src,
    const int* __restrict__ cnt, const int* __restrict__ boff,
    int* __restrict__ row_ptr, int* __restrict__ col, int N, int E4)
{
    __shared__ int loff[BN];
    __shared__ int lcur[BN];
    __shared__ int wsum[4];
    __shared__ int stage[STAGE_CAP];
    int b = blockIdx.x, tid = threadIdx.x;
    int base = boff[b];
    int total = boff[b + 1] - base;

    int lane = tid & 63, w = tid >> 6;
    int node = b * BN + tid;
    int v = 0;
    if (tid < BN && node < N) v = cnt[node];
    int incl = wave_incl_scan(v, lane);
    if (tid < BN && lane == 63) wsum[w] = incl;
    __syncthreads();
    if (tid < BN) {
        int wo = 0;
        for (int i = 0; i < w; ++i) wo += wsum[i];
        int excl = wo + incl - v;
        loff[tid] = excl;
        lcur[tid] = 0;
        if (node < N) row_ptr[node] = base + excl;
    }
    __syncthreads();

    if (total <= STAGE_CAP) {
        for (int i = tid; i < E4; i += 1024) {
            int4 d = dst4[i];
            int e = i * 4;
            if ((d.x >> BSH) == b) { int dl = d.x & (BN-1); int r = atomicAdd(&lcur[dl],1); stage[loff[dl]+r] = src[e]; }
            if ((d.y >> BSH) == b) { int dl = d.y & (BN-1); int r = atomicAdd(&lcur[dl],1); stage[loff[dl]+r] = src[e+1]; }
            if ((d.z >> BSH) == b) { int dl = d.z & (BN-1); int r = atomicAdd(&lcur[dl],1); stage[loff[dl]+r] = src[e+2]; }
            if ((d.w >> BSH) == b) { int dl = d.w & (BN-1); int r = atomicAdd(&lcur[dl],1); stage[loff[dl]+r] = src[e+3]; }
        }
        __syncthreads();
        for (int i = tid; i < total; i += 1024)
            col[base + i] = stage[i];
    } else {
        // overflow fallback: direct (uncoalesced) writes — correctness only
        for (int i = tid; i < E4; i += 1024) {
            int4 d = dst4[i];
            int e = i * 4;
            if ((d.x >> BSH) == b) { int dl = d.x & (BN-1); int r = atomicAdd(&lcur[dl],1); col[base+loff[dl]+r] = src[e]; }
            if ((d.y >> BSH) == b) { int dl = d.y & (BN-1); int r = atomicAdd(&lcur[dl],1); col[base+loff[dl]+r] = src[e+1]; }
            if ((d.z >> BSH) == b) { int dl = d.z & (BN-1); int r = atomicAdd(&lcur[dl],1); col[base+loff[dl]+r] = src[e+2]; }
            if ((d.w >> BSH) == b) { int dl = d.w & (BN-1); int r = atomicAdd(&lcur[dl],1); col[base+loff[dl]+r] = src[e+3]; }
        }
    }
}

// ---------------------------------------------------------------------------
// Softmax aggregation + relu + residual. Wave per node:
// 64 lanes = 4 edge-slots (es) x 16 feature-groups (fg, float4)
// ---------------------------------------------------------------------------
__global__ __launch_bounds__(256) void aggregate(
    const float4* __restrict__ hx4, const int* __restrict__ row_ptr,
    const int* __restrict__ col, const float* __restrict__ sarr,
    const float* __restrict__ darr, const float* __restrict__ bias,
    float* __restrict__ h, int n)
{
    __shared__ float aw[4][CAP];
    __shared__ int   ac[4][CAP];
    int tid = threadIdx.x;
    int wid = tid >> 6, lane = tid & 63, fg = lane & 15, es = lane >> 4;
    int v = blockIdx.x * 4 + wid;
    if (v >= n) return;

    int beg = row_ptr[v], end = row_ptr[v + 1];
    int deg = end - beg;
    float adi = darr[v];
    float m = -3.4e38f, s = 0.f;
    float4 acc = float4{0.f, 0.f, 0.f, 0.f};

    if (deg <= CAP) {
        for (int e = beg + lane; e < end; e += 64) {
            int c = col[e];
            float a = sarr[c] + adi;
            a = a > 0.f ? a : NEG_SLOPE * a;
            ac[wid][e - beg] = c;
            aw[wid][e - beg] = a;
            m = fmaxf(m, a);
        }
#pragma unroll
        for (int off = 32; off; off >>= 1) m = fmaxf(m, __shfl_xor(m, off));
        for (int i = lane; i < deg; i += 64) {
            float w = __expf(aw[wid][i] - m);
            aw[wid][i] = w; s += w;
        }
#pragma unroll
        for (int off = 32; off; off >>= 1) s += __shfl_xor(s, off);
#pragma unroll 2
        for (int i = es; i < deg; i += 4) {
            int c = ac[wid][i];
            float w = aw[wid][i];
            float4 hv = hx4[c * 16 + fg];
            acc.x += w * hv.x; acc.y += w * hv.y;
            acc.z += w * hv.z; acc.w += w * hv.w;
        }
    } else {
        for (int e = beg + lane; e < end; e += 64) {
            float a = sarr[col[e]] + adi;
            a = a > 0.f ? a : NEG_SLOPE * a;
            m = fmaxf(m, a);
        }
#pragma unroll
        for (int off = 32; off; off >>= 1) m = fmaxf(m, __shfl_xor(m, off));
        for (int e = beg + lane; e < end; e += 64) {
            float a = sarr[col[e]] + adi;
            a = a > 0.f ? a : NEG_SLOPE * a;
            s += __expf(a - m);
        }
#pragma unroll
        for (int off = 32; off; off >>= 1) s += __shfl_xor(s, off);
        for (int e = beg + es; e < end; e += 4) {
            int c = col[e];
            float a = sarr[c] + adi;
            a = a > 0.f ? a : NEG_SLOPE * a;
            float w = __expf(a - m);
            float4 hv = hx4[c * 16 + fg];
            acc.x += w * hv.x; acc.y += w * hv.y;
            acc.z += w * hv.z; acc.w += w * hv.w;
        }
    }

    acc.x += __shfl_xor(acc.x, 16); acc.y += __shfl_xor(acc.y, 16);
    acc.z += __shfl_xor(acc.z, 16); acc.w += __shfl_xor(acc.w, 16);
    acc.x += __shfl_xor(acc.x, 32); acc.y += __shfl_xor(acc.y, 32);
    acc.z += __shfl_xor(acc.z, 32); acc.w += __shfl_xor(acc.w, 32);

    if (es == 0) {
        float inv = (s > 0.f) ? 1.f / s : 0.f;
        float4 b4 = ((const float4*)bias)[fg];
        float4 o;
        o.x = fmaxf(acc.x * inv + b4.x, 0.f);
        o.y = fmaxf(acc.y * inv + b4.y, 0.f);
        o.z = fmaxf(acc.z * inv + b4.z, 0.f);
        o.w = fmaxf(acc.w * inv + b4.w, 0.f);
        float4* hp = (float4*)&h[v * DD + 4 * fg];
        float4 cur = *hp;
        cur.x += o.x; cur.y += o.y; cur.z += o.z; cur.w += o.w;
        *hp = cur;
    }
}

// ---------------------------------------------------------------------------
extern "C" void kernel_launch(void* const* d_in, const int* in_sizes, int n_in,
                              void* d_out, int out_size, void* d_ws, size_t ws_size,
                              hipStream_t stream)
{
    const float* x  = (const float*)d_in[0];
    const int*   ei = (const int*)d_in[1];
    const float* W0 = (const float*)d_in[4];
    const float* b0 = (const float*)d_in[5];
    const float* W1 = (const float*)d_in[6];
    const float* as1= (const float*)d_in[7];
    const float* ad1= (const float*)d_in[8];
    const float* b1 = (const float*)d_in[9];
    const float* W2 = (const float*)d_in[10];
    const float* as2= (const float*)d_in[11];
    const float* ad2= (const float*)d_in[12];
    const float* b2 = (const float*)d_in[13];

    int N = in_sizes[0] / DD;
    int E = in_sizes[1] / 2;
    int E4 = E / 4;                    // E is a multiple of 4 here (800000)
    int NB = (N + BN - 1) >> BSH;
    float* h = (float*)d_out;

    float* hx     = (float*)d_ws;              // N*64
    float* sarr   = hx + (size_t)N * DD;       // N
    float* darr   = sarr + N;                  // N
    int*   row_ptr= (int*)(darr + N);          // N+1
    int*   cnt    = row_ptr + (N + 1);         // N
    int*   btot   = cnt + N;                   // NB
    int*   boff   = btot + NB;                 // NB+1
    int*   colb   = boff + (NB + 1);           // E

    const int* src = ei;
    const int* dst = ei + E;
    const int4* dst4 = (const int4*)dst;

    int mm_tiles = (N + 63) / 64;
    int agg_blks = (N + 3) / 4;

    // ---- CSR build (no global atomics, coalesced writes) ----
    bucket_count<<<NB, 1024, 0, stream>>>(dst4, cnt, btot, N, E4);
    bucket_scan<<<1, 256, 0, stream>>>(btot, boff, row_ptr, NB, N, E);
    bucket_build<<<NB, 1024, 0, stream>>>(dst4, src, cnt, boff, row_ptr, colb, N, E4);

    // ---- layer 0 + GAT-1 matmul (fused) ----
    mm_fused<<<mm_tiles, 256, 0, stream>>>(x, W0, b0, W1, as1, ad1, h, hx, sarr, darr, N);
    aggregate<<<agg_blks, 256, 0, stream>>>((const float4*)hx, row_ptr, colb, sarr, darr, b1, h, N);

    // ---- GAT layer 2 ----
    mm_gat<<<mm_tiles, 256, 0, stream>>>(h, W2, as2, ad2, hx, sarr, darr, N);
    aggregate<<<agg_blks, 256, 0, stream>>>((const float4*)hx, row_ptr, colb, sarr, darr, b2, h, N);
}

// Round 5
// 232.092 us; speedup vs baseline: 1.9809x; 1.7351x over previous
//
#include <hip/hip_runtime.h>
#include <hip/hip_bf16.h>

#define DD 64
#define NEG_SLOPE 0.2f
#define HS 68          // padded LDS stride for h tile
#define CAP 128        // per-node alpha/col LDS cache in aggregate
#define BSH 8          // bucket = dst >> 8 (256 nodes per bucket)
#define BN  256        // nodes per bucket
#define NBLK 64        // edge-chunk blocks for the multi-split
#define STAGE_CAP 6144 // LDS col staging per bucket (expected ~4096 edges)

// ---------------------------------------------------------------------------
// Fused: h = relu(x@W0 + b0); hx = h@W1; sarr/darr = hx.a_src / hx.a_dst
// ---------------------------------------------------------------------------
__global__ __launch_bounds__(256) void mm_fused(
    const float* __restrict__ x,
    const float* __restrict__ W0, const float* __restrict__ b0,
    const float* __restrict__ W1,
    const float* __restrict__ a_src, const float* __restrict__ a_dst,
    float* __restrict__ h, float* __restrict__ hx,
    float* __restrict__ sarr, float* __restrict__ darr, int n)
{
    __shared__ float Wsh[DD * DD];
    __shared__ float Hsh[DD * HS];
    int tid = threadIdx.x;
    for (int i = tid * 4; i < DD * DD; i += 1024)
        *(float4*)&Wsh[i] = *(const float4*)&W0[i];

    int fg = tid & 15, ng = tid >> 4;
    int tile0 = blockIdx.x * 64;
    for (int p = 0; p < 4; ++p) {
        int nl = p * 16 + ng, gn = tile0 + nl;
        if (gn < n)
            *(float4*)&Hsh[nl * HS + 4 * fg] = *(const float4*)&x[gn * DD + 4 * fg];
    }
    __syncthreads();

    float4 acc[4];
#pragma unroll
    for (int j = 0; j < 4; ++j) acc[j] = float4{0.f, 0.f, 0.f, 0.f};
#pragma unroll 8
    for (int k = 0; k < DD; ++k) {
        float4 w4 = *(float4*)&Wsh[k * DD + 4 * fg];
#pragma unroll
        for (int j = 0; j < 4; ++j) {
            float hv = Hsh[(4 * ng + j) * HS + k];
            acc[j].x += hv * w4.x; acc[j].y += hv * w4.y;
            acc[j].z += hv * w4.z; acc[j].w += hv * w4.w;
        }
    }

    float4 b4 = *(const float4*)&b0[4 * fg];
    float4 o[4];
#pragma unroll
    for (int j = 0; j < 4; ++j) {
        o[j].x = fmaxf(acc[j].x + b4.x, 0.f);
        o[j].y = fmaxf(acc[j].y + b4.y, 0.f);
        o[j].z = fmaxf(acc[j].z + b4.z, 0.f);
        o[j].w = fmaxf(acc[j].w + b4.w, 0.f);
        int gn = tile0 + 4 * ng + j;
        if (gn < n) *(float4*)&h[gn * DD + 4 * fg] = o[j];
    }
    __syncthreads();

#pragma unroll
    for (int j = 0; j < 4; ++j)
        *(float4*)&Hsh[(4 * ng + j) * HS + 4 * fg] = o[j];
    for (int i = tid * 4; i < DD * DD; i += 1024)
        *(float4*)&Wsh[i] = *(const float4*)&W1[i];
    __syncthreads();

#pragma unroll
    for (int j = 0; j < 4; ++j) acc[j] = float4{0.f, 0.f, 0.f, 0.f};
#pragma unroll 8
    for (int k = 0; k < DD; ++k) {
        float4 w4 = *(float4*)&Wsh[k * DD + 4 * fg];
#pragma unroll
        for (int j = 0; j < 4; ++j) {
            float hv = Hsh[(4 * ng + j) * HS + k];
            acc[j].x += hv * w4.x; acc[j].y += hv * w4.y;
            acc[j].z += hv * w4.z; acc[j].w += hv * w4.w;
        }
    }

    float4 as4 = *(const float4*)&a_src[4 * fg];
    float4 ad4 = *(const float4*)&a_dst[4 * fg];
#pragma unroll
    for (int j = 0; j < 4; ++j) {
        int gn = tile0 + 4 * ng + j;
        if (gn < n) *(float4*)&hx[gn * DD + 4 * fg] = acc[j];
        float ps = acc[j].x * as4.x + acc[j].y * as4.y + acc[j].z * as4.z + acc[j].w * as4.w;
        float pd = acc[j].x * ad4.x + acc[j].y * ad4.y + acc[j].z * ad4.z + acc[j].w * ad4.w;
#pragma unroll
        for (int off = 8; off; off >>= 1) {
            ps += __shfl_xor(ps, off);
            pd += __shfl_xor(pd, off);
        }
        if (fg == 0 && gn < n) { sarr[gn] = ps; darr[gn] = pd; }
    }
}

// ---------------------------------------------------------------------------
// Plain GAT matmul (layer 2)
// ---------------------------------------------------------------------------
__global__ __launch_bounds__(256) void mm_gat(
    const float* __restrict__ h, const float* __restrict__ W,
    const float* __restrict__ a_src, const float* __restrict__ a_dst,
    float* __restrict__ hx, float* __restrict__ sarr, float* __restrict__ darr,
    int n)
{
    __shared__ float Wsh[DD * DD];
    __shared__ float Hsh[DD * HS];
    int tid = threadIdx.x;
    for (int i = tid * 4; i < DD * DD; i += 1024)
        *(float4*)&Wsh[i] = *(const float4*)&W[i];

    int fg = tid & 15, ng = tid >> 4;
    int tile0 = blockIdx.x * 64;
    for (int p = 0; p < 4; ++p) {
        int nl = p * 16 + ng, gn = tile0 + nl;
        if (gn < n)
            *(float4*)&Hsh[nl * HS + 4 * fg] = *(const float4*)&h[gn * DD + 4 * fg];
    }
    __syncthreads();

    float4 acc[4];
#pragma unroll
    for (int j = 0; j < 4; ++j) acc[j] = float4{0.f, 0.f, 0.f, 0.f};
#pragma unroll 8
    for (int k = 0; k < DD; ++k) {
        float4 w4 = *(float4*)&Wsh[k * DD + 4 * fg];
#pragma unroll
        for (int j = 0; j < 4; ++j) {
            float hv = Hsh[(4 * ng + j) * HS + k];
            acc[j].x += hv * w4.x; acc[j].y += hv * w4.y;
            acc[j].z += hv * w4.z; acc[j].w += hv * w4.w;
        }
    }

    float4 as4 = *(const float4*)&a_src[4 * fg];
    float4 ad4 = *(const float4*)&a_dst[4 * fg];
#pragma unroll
    for (int j = 0; j < 4; ++j) {
        int gn = tile0 + 4 * ng + j;
        if (gn < n) *(float4*)&hx[gn * DD + 4 * fg] = acc[j];
        float ps = acc[j].x * as4.x + acc[j].y * as4.y + acc[j].z * as4.z + acc[j].w * as4.w;
        float pd = acc[j].x * ad4.x + acc[j].y * ad4.y + acc[j].z * ad4.z + acc[j].w * ad4.w;
#pragma unroll
        for (int off = 8; off; off >>= 1) {
            ps += __shfl_xor(ps, off);
            pd += __shfl_xor(pd, off);
        }
        if (fg == 0 && gn < n) { sarr[gn] = ps; darr[gn] = pd; }
    }
}

// ---------------------------------------------------------------------------
// CSR build — privatized multi-split. Zero global atomics, deterministic.
// ---------------------------------------------------------------------------
__device__ __forceinline__ int wave_incl_scan(int v, int lane)
{
#pragma unroll
    for (int off = 1; off < 64; off <<= 1) {
        int t = __shfl_up(v, off);
        if (lane >= off) v += t;
    }
    return v;
}

// 1: per-chunk bucket histogram -> cnts[NBLK][NB]
__global__ __launch_bounds__(1024) void chunk_count(
    const int4* __restrict__ dst4, const int* __restrict__ dst,
    int* __restrict__ cnts, int NB, int E4, int E, int C4)
{
    __shared__ int lh[BN];
    int k = blockIdx.x, tid = threadIdx.x;
    for (int i = tid; i < NB; i += 1024) lh[i] = 0;
    __syncthreads();
    int i0 = k * C4, i1 = min(i0 + C4, E4);
    for (int i = i0 + tid; i < i1; i += 1024) {
        int4 d = dst4[i];
        atomicAdd(&lh[d.x >> BSH], 1);
        atomicAdd(&lh[d.y >> BSH], 1);
        atomicAdd(&lh[d.z >> BSH], 1);
        atomicAdd(&lh[d.w >> BSH], 1);
    }
    if (k == NBLK - 1) {
        for (int e = E4 * 4 + tid; e < E; e += 1024)
            atomicAdd(&lh[dst[e] >> BSH], 1);
    }
    __syncthreads();
    for (int i = tid; i < NB; i += 1024) cnts[k * NB + i] = lh[i];
}

// 2: bucket totals, exclusive scan -> boff; per-(block,bucket) bases -> cbase
__global__ __launch_bounds__(256) void csr_scan(
    const int* __restrict__ cnts, int* __restrict__ boff, int* __restrict__ cbase,
    int* __restrict__ row_ptr, int NB, int N, int E)
{
    __shared__ int wsum[4];
    int t = threadIdx.x, lane = t & 63, w = t >> 6;
    int sum = 0;
    if (t < NB)
        for (int k = 0; k < NBLK; ++k) sum += cnts[k * NB + t];
    int incl = wave_incl_scan(sum, lane);
    if (lane == 63) wsum[w] = incl;
    __syncthreads();
    int wo = 0;
    for (int i = 0; i < w; ++i) wo += wsum[i];
    int excl = wo + incl - sum;
    if (t < NB) {
        boff[t] = excl;
        int run = excl;
        for (int k = 0; k < NBLK; ++k) {
            cbase[k * NB + t] = run;
            run += cnts[k * NB + t];
        }
    }
    if (t == 0) { boff[NB] = E; row_ptr[N] = E; }
}

// 3: scatter packed (dstLocal<<24)|src into bucket-clustered ebuf
__global__ __launch_bounds__(1024) void chunk_scatter(
    const int4* __restrict__ dst4, const int4* __restrict__ src4,
    const int* __restrict__ dst, const int* __restrict__ src,
    const int* __restrict__ cbase, int* __restrict__ ebuf,
    int NB, int E4, int E, int C4)
{
    __shared__ int lcur[BN];
    int k = blockIdx.x, tid = threadIdx.x;
    for (int i = tid; i < NB; i += 1024) lcur[i] = cbase[k * NB + i];
    __syncthreads();
    int i0 = k * C4, i1 = min(i0 + C4, E4);
    for (int i = i0 + tid; i < i1; i += 1024) {
        int4 d = dst4[i];
        int4 s = src4[i];
        int b, p;
        b = d.x >> BSH; p = atomicAdd(&lcur[b], 1); ebuf[p] = ((d.x & (BN - 1)) << 24) | s.x;
        b = d.y >> BSH; p = atomicAdd(&lcur[b], 1); ebuf[p] = ((d.y & (BN - 1)) << 24) | s.y;
        b = d.z >> BSH; p = atomicAdd(&lcur[b], 1); ebuf[p] = ((d.z & (BN - 1)) << 24) | s.z;
        b = d.w >> BSH; p = atomicAdd(&lcur[b], 1); ebuf[p] = ((d.w & (BN - 1)) << 24) | s.w;
    }
    if (k == NBLK - 1) {
        for (int e = E4 * 4 + tid; e < E; e += 1024) {
            int d = dst[e];
            int b = d >> BSH;
            int p = atomicAdd(&lcur[b], 1);
            ebuf[p] = ((d & (BN - 1)) << 24) | src[e];
        }
    }
}

// 4: per-bucket node ordering: row_ptr + col (contiguous slice only)
__global__ __launch_bounds__(512) void group_build(
    const int* __restrict__ ebuf, const int* __restrict__ boff,
    int* __restrict__ row_ptr, int* __restrict__ col, int N)
{
    __shared__ int lcnt[BN];
    __shared__ int loff[BN];
    __shared__ int lcur[BN];
    __shared__ int wsum[4];
    __shared__ int stage[STAGE_CAP];
    int b = blockIdx.x, tid = threadIdx.x;
    int e0 = boff[b], e1 = boff[b + 1];
    int total = e1 - e0;
    if (tid < BN) { lcnt[tid] = 0; lcur[tid] = 0; }
    __syncthreads();
    for (int e = e0 + tid; e < e1; e += 512)
        atomicAdd(&lcnt[((unsigned)ebuf[e]) >> 24], 1);
    __syncthreads();
    int lane = tid & 63, w = tid >> 6;
    int v = (tid < BN) ? lcnt[tid] : 0;
    int incl = wave_incl_scan(v, lane);
    if (tid < BN && lane == 63) wsum[w] = incl;
    __syncthreads();
    if (tid < BN) {
        int wo = 0;
        for (int i = 0; i < w; ++i) wo += wsum[i];
        int excl = wo + incl - v;
        loff[tid] = excl;
        int node = b * BN + tid;
        if (node < N) row_ptr[node] = e0 + excl;
    }
    __syncthreads();
    if (total <= STAGE_CAP) {
        for (int e = e0 + tid; e < e1; e += 512) {
            int p = ebuf[e];
            int dl = ((unsigned)p) >> 24;
            int r = atomicAdd(&lcur[dl], 1);
            stage[loff[dl] + r] = p & 0xFFFFFF;
        }
        __syncthreads();
        for (int i = tid; i < total; i += 512)
            col[e0 + i] = stage[i];
    } else {
        // overflow fallback (correctness only)
        for (int e = e0 + tid; e < e1; e += 512) {
            int p = ebuf[e];
            int dl = ((unsigned)p) >> 24;
            int r = atomicAdd(&lcur[dl], 1);
            col[e0 + loff[dl] + r] = p & 0xFFFFFF;
        }
    }
}

// ---------------------------------------------------------------------------
// Softmax aggregation + relu + residual. Wave per node:
// 64 lanes = 4 edge-slots (es) x 16 feature-groups (fg, float4)
// ---------------------------------------------------------------------------
__global__ __launch_bounds__(256) void aggregate(
    const float4* __restrict__ hx4, const int* __restrict__ row_ptr,
    const int* __restrict__ col, const float* __restrict__ sarr,
    const float* __restrict__ darr, const float* __restrict__ bias,
    float* __restrict__ h, int n)
{
    __shared__ float aw[4][CAP];
    __shared__ int   ac[4][CAP];
    int tid = threadIdx.x;
    int wid = tid >> 6, lane = tid & 63, fg = lane & 15, es = lane >> 4;
    int v = blockIdx.x * 4 + wid;
    if (v >= n) return;

    int beg = row_ptr[v], end = row_ptr[v + 1];
    int deg = end - beg;
    float adi = darr[v];
    float m = -3.4e38f, s = 0.f;
    float4 acc = float4{0.f, 0.f, 0.f, 0.f};

    if (deg <= CAP) {
        for (int e = beg + lane; e < end; e += 64) {
            int c = col[e];
            float a = sarr[c] + adi;
            a = a > 0.f ? a : NEG_SLOPE * a;
            ac[wid][e - beg] = c;
            aw[wid][e - beg] = a;
            m = fmaxf(m, a);
        }
#pragma unroll
        for (int off = 32; off; off >>= 1) m = fmaxf(m, __shfl_xor(m, off));
        for (int i = lane; i < deg; i += 64) {
            float w = __expf(aw[wid][i] - m);
            aw[wid][i] = w; s += w;
        }
#pragma unroll
        for (int off = 32; off; off >>= 1) s += __shfl_xor(s, off);
#pragma unroll 2
        for (int i = es; i < deg; i += 4) {
            int c = ac[wid][i];
            float w = aw[wid][i];
            float4 hv = hx4[c * 16 + fg];
            acc.x += w * hv.x; acc.y += w * hv.y;
            acc.z += w * hv.z; acc.w += w * hv.w;
        }
    } else {
        for (int e = beg + lane; e < end; e += 64) {
            float a = sarr[col[e]] + adi;
            a = a > 0.f ? a : NEG_SLOPE * a;
            m = fmaxf(m, a);
        }
#pragma unroll
        for (int off = 32; off; off >>= 1) m = fmaxf(m, __shfl_xor(m, off));
        for (int e = beg + lane; e < end; e += 64) {
            float a = sarr[col[e]] + adi;
            a = a > 0.f ? a : NEG_SLOPE * a;
            s += __expf(a - m);
        }
#pragma unroll
        for (int off = 32; off; off >>= 1) s += __shfl_xor(s, off);
        for (int e = beg + es; e < end; e += 4) {
            int c = col[e];
            float a = sarr[c] + adi;
            a = a > 0.f ? a : NEG_SLOPE * a;
            float w = __expf(a - m);
            float4 hv = hx4[c * 16 + fg];
            acc.x += w * hv.x; acc.y += w * hv.y;
            acc.z += w * hv.z; acc.w += w * hv.w;
        }
    }

    acc.x += __shfl_xor(acc.x, 16); acc.y += __shfl_xor(acc.y, 16);
    acc.z += __shfl_xor(acc.z, 16); acc.w += __shfl_xor(acc.w, 16);
    acc.x += __shfl_xor(acc.x, 32); acc.y += __shfl_xor(acc.y, 32);
    acc.z += __shfl_xor(acc.z, 32); acc.w += __shfl_xor(acc.w, 32);

    if (es == 0) {
        float inv = (s > 0.f) ? 1.f / s : 0.f;
        float4 b4 = ((const float4*)bias)[fg];
        float4 o;
        o.x = fmaxf(acc.x * inv + b4.x, 0.f);
        o.y = fmaxf(acc.y * inv + b4.y, 0.f);
        o.z = fmaxf(acc.z * inv + b4.z, 0.f);
        o.w = fmaxf(acc.w * inv + b4.w, 0.f);
        float4* hp = (float4*)&h[v * DD + 4 * fg];
        float4 cur = *hp;
        cur.x += o.x; cur.y += o.y; cur.z += o.z; cur.w += o.w;
        *hp = cur;
    }
}

// ---------------------------------------------------------------------------
extern "C" void kernel_launch(void* const* d_in, const int* in_sizes, int n_in,
                              void* d_out, int out_size, void* d_ws, size_t ws_size,
                              hipStream_t stream)
{
    const float* x  = (const float*)d_in[0];
    const int*   ei = (const int*)d_in[1];
    const float* W0 = (const float*)d_in[4];
    const float* b0 = (const float*)d_in[5];
    const float* W1 = (const float*)d_in[6];
    const float* as1= (const float*)d_in[7];
    const float* ad1= (const float*)d_in[8];
    const float* b1 = (const float*)d_in[9];
    const float* W2 = (const float*)d_in[10];
    const float* as2= (const float*)d_in[11];
    const float* ad2= (const float*)d_in[12];
    const float* b2 = (const float*)d_in[13];

    int N = in_sizes[0] / DD;
    int E = in_sizes[1] / 2;
    int E4 = E >> 2;
    int C4 = (E4 + NBLK - 1) / NBLK;
    int NB = (N + BN - 1) >> BSH;
    float* h = (float*)d_out;

    float* hx     = (float*)d_ws;              // N*64
    float* sarr   = hx + (size_t)N * DD;       // N
    float* darr   = sarr + N;                  // N
    int*   row_ptr= (int*)(darr + N);          // N+1
    int*   cnts   = row_ptr + (N + 1);         // NBLK*NB
    int*   cbase  = cnts + NBLK * NB;          // NBLK*NB
    int*   boff   = cbase + NBLK * NB;         // NB+1
    int*   ebuf   = boff + (NB + 1);           // E
    int*   colb   = ebuf + E;                  // E

    const int* src = ei;
    const int* dst = ei + E;
    const int4* dst4 = (const int4*)dst;
    const int4* src4 = (const int4*)src;

    int mm_tiles = (N + 63) / 64;
    int agg_blks = (N + 3) / 4;

    // ---- CSR build: privatized multi-split (no global atomics) ----
    chunk_count<<<NBLK, 1024, 0, stream>>>(dst4, dst, cnts, NB, E4, E, C4);
    csr_scan<<<1, 256, 0, stream>>>(cnts, boff, cbase, row_ptr, NB, N, E);
    chunk_scatter<<<NBLK, 1024, 0, stream>>>(dst4, src4, dst, src, cbase, ebuf, NB, E4, E, C4);
    group_build<<<NB, 512, 0, stream>>>(ebuf, boff, row_ptr, colb, N);

    // ---- layer 0 + GAT-1 matmul (fused) ----
    mm_fused<<<mm_tiles, 256, 0, stream>>>(x, W0, b0, W1, as1, ad1, h, hx, sarr, darr, N);
    aggregate<<<agg_blks, 256, 0, stream>>>((const float4*)hx, row_ptr, colb, sarr, darr, b1, h, N);

    // ---- GAT layer 2 ----
    mm_gat<<<mm_tiles, 256, 0, stream>>>(h, W2, as2, ad2, hx, sarr, darr, N);
    aggregate<<<agg_blks, 256, 0, stream>>>((const float4*)hx, row_ptr, colb, sarr, darr, b2, h, N);
}

// Round 6
// 216.702 us; speedup vs baseline: 2.1216x; 1.0710x over previous
//
#include <hip/hip_runtime.h>
#include <hip/hip_bf16.h>

#define DD 64
#define NEG_SLOPE 0.2f
#define HS 68          // padded LDS stride for h tile
#define CAP 64         // per-node alpha/col LDS cache in aggregate (deg~Pois(16))
#define BSH 8          // bucket = dst >> 8 (256 nodes per bucket)
#define BN  256        // nodes per bucket
#define NBMAX 256      // max buckets supported by LDS hists
#define NBLK 256       // edge-chunk blocks for the multi-split
#define STAGE_CAP 6144 // LDS col staging per bucket (expected ~4096 edges)

// fp32 -> bf16 with round-to-nearest-even (finite inputs)
__device__ __forceinline__ unsigned short f2bf(float f)
{
    unsigned u = __float_as_uint(f);
    u += 0x7FFFu + ((u >> 16) & 1u);
    return (unsigned short)(u >> 16);
}
__device__ __forceinline__ float bf2f(unsigned short b)
{
    return __uint_as_float(((unsigned)b) << 16);
}

// ---------------------------------------------------------------------------
// Fused: h = relu(x@W0 + b0); hx(bf16) = h@W1; sarr/darr = hx.a_src / hx.a_dst
// ---------------------------------------------------------------------------
__global__ __launch_bounds__(256) void mm_fused(
    const float* __restrict__ x,
    const float* __restrict__ W0, const float* __restrict__ b0,
    const float* __restrict__ W1,
    const float* __restrict__ a_src, const float* __restrict__ a_dst,
    float* __restrict__ h, ushort4* __restrict__ hxb4,
    float* __restrict__ sarr, float* __restrict__ darr, int n)
{
    __shared__ float Wsh[DD * DD];
    __shared__ float Hsh[DD * HS];
    int tid = threadIdx.x;
    for (int i = tid * 4; i < DD * DD; i += 1024)
        *(float4*)&Wsh[i] = *(const float4*)&W0[i];

    int fg = tid & 15, ng = tid >> 4;
    int tile0 = blockIdx.x * 64;
    for (int p = 0; p < 4; ++p) {
        int nl = p * 16 + ng, gn = tile0 + nl;
        if (gn < n)
            *(float4*)&Hsh[nl * HS + 4 * fg] = *(const float4*)&x[gn * DD + 4 * fg];
    }
    __syncthreads();

    float4 acc[4];
#pragma unroll
    for (int j = 0; j < 4; ++j) acc[j] = float4{0.f, 0.f, 0.f, 0.f};
#pragma unroll 8
    for (int k = 0; k < DD; ++k) {
        float4 w4 = *(float4*)&Wsh[k * DD + 4 * fg];
#pragma unroll
        for (int j = 0; j < 4; ++j) {
            float hv = Hsh[(4 * ng + j) * HS + k];
            acc[j].x += hv * w4.x; acc[j].y += hv * w4.y;
            acc[j].z += hv * w4.z; acc[j].w += hv * w4.w;
        }
    }

    float4 b4 = *(const float4*)&b0[4 * fg];
    float4 o[4];
#pragma unroll
    for (int j = 0; j < 4; ++j) {
        o[j].x = fmaxf(acc[j].x + b4.x, 0.f);
        o[j].y = fmaxf(acc[j].y + b4.y, 0.f);
        o[j].z = fmaxf(acc[j].z + b4.z, 0.f);
        o[j].w = fmaxf(acc[j].w + b4.w, 0.f);
        int gn = tile0 + 4 * ng + j;
        if (gn < n) *(float4*)&h[gn * DD + 4 * fg] = o[j];
    }
    __syncthreads();

#pragma unroll
    for (int j = 0; j < 4; ++j)
        *(float4*)&Hsh[(4 * ng + j) * HS + 4 * fg] = o[j];
    for (int i = tid * 4; i < DD * DD; i += 1024)
        *(float4*)&Wsh[i] = *(const float4*)&W1[i];
    __syncthreads();

#pragma unroll
    for (int j = 0; j < 4; ++j) acc[j] = float4{0.f, 0.f, 0.f, 0.f};
#pragma unroll 8
    for (int k = 0; k < DD; ++k) {
        float4 w4 = *(float4*)&Wsh[k * DD + 4 * fg];
#pragma unroll
        for (int j = 0; j < 4; ++j) {
            float hv = Hsh[(4 * ng + j) * HS + k];
            acc[j].x += hv * w4.x; acc[j].y += hv * w4.y;
            acc[j].z += hv * w4.z; acc[j].w += hv * w4.w;
        }
    }

    float4 as4 = *(const float4*)&a_src[4 * fg];
    float4 ad4 = *(const float4*)&a_dst[4 * fg];
#pragma unroll
    for (int j = 0; j < 4; ++j) {
        int gn = tile0 + 4 * ng + j;
        if (gn < n) {
            ushort4 hb;
            hb.x = f2bf(acc[j].x); hb.y = f2bf(acc[j].y);
            hb.z = f2bf(acc[j].z); hb.w = f2bf(acc[j].w);
            hxb4[gn * 16 + fg] = hb;
        }
        float ps = acc[j].x * as4.x + acc[j].y * as4.y + acc[j].z * as4.z + acc[j].w * as4.w;
        float pd = acc[j].x * ad4.x + acc[j].y * ad4.y + acc[j].z * ad4.z + acc[j].w * ad4.w;
#pragma unroll
        for (int off = 8; off; off >>= 1) {
            ps += __shfl_xor(ps, off);
            pd += __shfl_xor(pd, off);
        }
        if (fg == 0 && gn < n) { sarr[gn] = ps; darr[gn] = pd; }
    }
}

// ---------------------------------------------------------------------------
// Plain GAT matmul (layer 2), hx output in bf16
// ---------------------------------------------------------------------------
__global__ __launch_bounds__(256) void mm_gat(
    const float* __restrict__ h, const float* __restrict__ W,
    const float* __restrict__ a_src, const float* __restrict__ a_dst,
    ushort4* __restrict__ hxb4, float* __restrict__ sarr, float* __restrict__ darr,
    int n)
{
    __shared__ float Wsh[DD * DD];
    __shared__ float Hsh[DD * HS];
    int tid = threadIdx.x;
    for (int i = tid * 4; i < DD * DD; i += 1024)
        *(float4*)&Wsh[i] = *(const float4*)&W[i];

    int fg = tid & 15, ng = tid >> 4;
    int tile0 = blockIdx.x * 64;
    for (int p = 0; p < 4; ++p) {
        int nl = p * 16 + ng, gn = tile0 + nl;
        if (gn < n)
            *(float4*)&Hsh[nl * HS + 4 * fg] = *(const float4*)&h[gn * DD + 4 * fg];
    }
    __syncthreads();

    float4 acc[4];
#pragma unroll
    for (int j = 0; j < 4; ++j) acc[j] = float4{0.f, 0.f, 0.f, 0.f};
#pragma unroll 8
    for (int k = 0; k < DD; ++k) {
        float4 w4 = *(float4*)&Wsh[k * DD + 4 * fg];
#pragma unroll
        for (int j = 0; j < 4; ++j) {
            float hv = Hsh[(4 * ng + j) * HS + k];
            acc[j].x += hv * w4.x; acc[j].y += hv * w4.y;
            acc[j].z += hv * w4.z; acc[j].w += hv * w4.w;
        }
    }

    float4 as4 = *(const float4*)&a_src[4 * fg];
    float4 ad4 = *(const float4*)&a_dst[4 * fg];
#pragma unroll
    for (int j = 0; j < 4; ++j) {
        int gn = tile0 + 4 * ng + j;
        if (gn < n) {
            ushort4 hb;
            hb.x = f2bf(acc[j].x); hb.y = f2bf(acc[j].y);
            hb.z = f2bf(acc[j].z); hb.w = f2bf(acc[j].w);
            hxb4[gn * 16 + fg] = hb;
        }
        float ps = acc[j].x * as4.x + acc[j].y * as4.y + acc[j].z * as4.z + acc[j].w * as4.w;
        float pd = acc[j].x * ad4.x + acc[j].y * ad4.y + acc[j].z * ad4.z + acc[j].w * ad4.w;
#pragma unroll
        for (int off = 8; off; off >>= 1) {
            ps += __shfl_xor(ps, off);
            pd += __shfl_xor(pd, off);
        }
        if (fg == 0 && gn < n) { sarr[gn] = ps; darr[gn] = pd; }
    }
}

// ---------------------------------------------------------------------------
// CSR build — privatized multi-split. Zero global atomics, deterministic.
// ---------------------------------------------------------------------------
__device__ __forceinline__ int wave_incl_scan(int v, int lane)
{
#pragma unroll
    for (int off = 1; off < 64; off <<= 1) {
        int t = __shfl_up(v, off);
        if (lane >= off) v += t;
    }
    return v;
}

// 1: per-chunk bucket histogram -> cnts[NBLK][NB]
__global__ __launch_bounds__(512) void chunk_count(
    const int4* __restrict__ dst4, const int* __restrict__ dst,
    int* __restrict__ cnts, int NB, int E4, int E, int C4)
{
    __shared__ int lh[NBMAX];
    int k = blockIdx.x, tid = threadIdx.x;
    for (int i = tid; i < NB; i += 512) lh[i] = 0;
    __syncthreads();
    int i0 = k * C4, i1 = min(i0 + C4, E4);
    for (int i = i0 + tid; i < i1; i += 512) {
        int4 d = dst4[i];
        atomicAdd(&lh[d.x >> BSH], 1);
        atomicAdd(&lh[d.y >> BSH], 1);
        atomicAdd(&lh[d.z >> BSH], 1);
        atomicAdd(&lh[d.w >> BSH], 1);
    }
    if (k == NBLK - 1) {
        for (int e = E4 * 4 + tid; e < E; e += 512)
            atomicAdd(&lh[dst[e] >> BSH], 1);
    }
    __syncthreads();
    for (int i = tid; i < NB; i += 512) cnts[k * NB + i] = lh[i];
}

// 2: bucket totals, exclusive scan -> boff; per-(block,bucket) bases -> cbase
__global__ __launch_bounds__(256) void csr_scan(
    const int* __restrict__ cnts, int* __restrict__ boff, int* __restrict__ cbase,
    int* __restrict__ row_ptr, int NB, int N, int E)
{
    __shared__ int wsum[4];
    int t = threadIdx.x, lane = t & 63, w = t >> 6;
    int sum = 0;
    if (t < NB)
        for (int k = 0; k < NBLK; ++k) sum += cnts[k * NB + t];
    int incl = wave_incl_scan(sum, lane);
    if (lane == 63) wsum[w] = incl;
    __syncthreads();
    int wo = 0;
    for (int i = 0; i < w; ++i) wo += wsum[i];
    int excl = wo + incl - sum;
    if (t < NB) {
        boff[t] = excl;
        int run = excl;
        for (int k = 0; k < NBLK; ++k) {
            cbase[k * NB + t] = run;
            run += cnts[k * NB + t];
        }
    }
    if (t == 0) { boff[NB] = E; row_ptr[N] = E; }
}

// 3: scatter packed (dstLocal<<24)|src into bucket-clustered ebuf
__global__ __launch_bounds__(512) void chunk_scatter(
    const int4* __restrict__ dst4, const int4* __restrict__ src4,
    const int* __restrict__ dst, const int* __restrict__ src,
    const int* __restrict__ cbase, int* __restrict__ ebuf,
    int NB, int E4, int E, int C4)
{
    __shared__ int lcur[NBMAX];
    int k = blockIdx.x, tid = threadIdx.x;
    for (int i = tid; i < NB; i += 512) lcur[i] = cbase[k * NB + i];
    __syncthreads();
    int i0 = k * C4, i1 = min(i0 + C4, E4);
    for (int i = i0 + tid; i < i1; i += 512) {
        int4 d = dst4[i];
        int4 s = src4[i];
        int b, p;
        b = d.x >> BSH; p = atomicAdd(&lcur[b], 1); ebuf[p] = ((d.x & (BN - 1)) << 24) | s.x;
        b = d.y >> BSH; p = atomicAdd(&lcur[b], 1); ebuf[p] = ((d.y & (BN - 1)) << 24) | s.y;
        b = d.z >> BSH; p = atomicAdd(&lcur[b], 1); ebuf[p] = ((d.z & (BN - 1)) << 24) | s.z;
        b = d.w >> BSH; p = atomicAdd(&lcur[b], 1); ebuf[p] = ((d.w & (BN - 1)) << 24) | s.w;
    }
    if (k == NBLK - 1) {
        for (int e = E4 * 4 + tid; e < E; e += 512) {
            int d = dst[e];
            int b = d >> BSH;
            int p = atomicAdd(&lcur[b], 1);
            ebuf[p] = ((d & (BN - 1)) << 24) | src[e];
        }
    }
}

// 4: per-bucket node ordering: row_ptr + col (contiguous slice only)
__global__ __launch_bounds__(512) void group_build(
    const int* __restrict__ ebuf, const int* __restrict__ boff,
    int* __restrict__ row_ptr, int* __restrict__ col, int N)
{
    __shared__ int lcnt[BN];
    __shared__ int loff[BN];
    __shared__ int lcur[BN];
    __shared__ int wsum[4];
    __shared__ int stage[STAGE_CAP];
    int b = blockIdx.x, tid = threadIdx.x;
    int e0 = boff[b], e1 = boff[b + 1];
    int total = e1 - e0;
    if (tid < BN) { lcnt[tid] = 0; lcur[tid] = 0; }
    __syncthreads();
    for (int e = e0 + tid; e < e1; e += 512)
        atomicAdd(&lcnt[((unsigned)ebuf[e]) >> 24], 1);
    __syncthreads();
    int lane = tid & 63, w = tid >> 6;
    int v = (tid < BN) ? lcnt[tid] : 0;
    int incl = wave_incl_scan(v, lane);
    if (tid < BN && lane == 63) wsum[w] = incl;
    __syncthreads();
    if (tid < BN) {
        int wo = 0;
        for (int i = 0; i < w; ++i) wo += wsum[i];
        int excl = wo + incl - v;
        loff[tid] = excl;
        int node = b * BN + tid;
        if (node < N) row_ptr[node] = e0 + excl;
    }
    __syncthreads();
    if (total <= STAGE_CAP) {
        for (int e = e0 + tid; e < e1; e += 512) {
            int p = ebuf[e];
            int dl = ((unsigned)p) >> 24;
            int r = atomicAdd(&lcur[dl], 1);
            stage[loff[dl] + r] = p & 0xFFFFFF;
        }
        __syncthreads();
        for (int i = tid; i < total; i += 512)
            col[e0 + i] = stage[i];
    } else {
        for (int e = e0 + tid; e < e1; e += 512) {
            int p = ebuf[e];
            int dl = ((unsigned)p) >> 24;
            int r = atomicAdd(&lcur[dl], 1);
            col[e0 + loff[dl] + r] = p & 0xFFFFFF;
        }
    }
}

// ---------------------------------------------------------------------------
// Softmax aggregation + relu + residual. Wave per node:
// 64 lanes = 4 edge-slots (es) x 16 feature-groups (fg); hx gathers in bf16
// ---------------------------------------------------------------------------
__global__ __launch_bounds__(256) void aggregate(
    const ushort4* __restrict__ hxb4, const int* __restrict__ row_ptr,
    const int* __restrict__ col, const float* __restrict__ sarr,
    const float* __restrict__ darr, const float* __restrict__ bias,
    float* __restrict__ h, int n)
{
    __shared__ float aw[4][CAP];
    __shared__ int   ac[4][CAP];
    int tid = threadIdx.x;
    int wid = tid >> 6, lane = tid & 63, fg = lane & 15, es = lane >> 4;
    int v = blockIdx.x * 4 + wid;
    if (v >= n) return;

    int beg = row_ptr[v], end = row_ptr[v + 1];
    int deg = end - beg;
    float adi = darr[v];
    float m = -3.4e38f, s = 0.f;
    float4 acc = float4{0.f, 0.f, 0.f, 0.f};

    if (deg <= CAP) {
        for (int e = beg + lane; e < end; e += 64) {
            int c = col[e];
            float a = sarr[c] + adi;
            a = a > 0.f ? a : NEG_SLOPE * a;
            ac[wid][e - beg] = c;
            aw[wid][e - beg] = a;
            m = fmaxf(m, a);
        }
#pragma unroll
        for (int off = 32; off; off >>= 1) m = fmaxf(m, __shfl_xor(m, off));
        for (int i = lane; i < deg; i += 64) {
            float w = __expf(aw[wid][i] - m);
            aw[wid][i] = w; s += w;
        }
#pragma unroll
        for (int off = 32; off; off >>= 1) s += __shfl_xor(s, off);
#pragma unroll 2
        for (int i = es; i < deg; i += 4) {
            int c = ac[wid][i];
            float w = aw[wid][i];
            ushort4 u = hxb4[c * 16 + fg];
            acc.x += w * bf2f(u.x); acc.y += w * bf2f(u.y);
            acc.z += w * bf2f(u.z); acc.w += w * bf2f(u.w);
        }
    } else {
        for (int e = beg + lane; e < end; e += 64) {
            float a = sarr[col[e]] + adi;
            a = a > 0.f ? a : NEG_SLOPE * a;
            m = fmaxf(m, a);
        }
#pragma unroll
        for (int off = 32; off; off >>= 1) m = fmaxf(m, __shfl_xor(m, off));
        for (int e = beg + lane; e < end; e += 64) {
            float a = sarr[col[e]] + adi;
            a = a > 0.f ? a : NEG_SLOPE * a;
            s += __expf(a - m);
        }
#pragma unroll
        for (int off = 32; off; off >>= 1) s += __shfl_xor(s, off);
        for (int e = beg + es; e < end; e += 4) {
            int c = col[e];
            float a = sarr[c] + adi;
            a = a > 0.f ? a : NEG_SLOPE * a;
            float w = __expf(a - m);
            ushort4 u = hxb4[c * 16 + fg];
            acc.x += w * bf2f(u.x); acc.y += w * bf2f(u.y);
            acc.z += w * bf2f(u.z); acc.w += w * bf2f(u.w);
        }
    }

    acc.x += __shfl_xor(acc.x, 16); acc.y += __shfl_xor(acc.y, 16);
    acc.z += __shfl_xor(acc.z, 16); acc.w += __shfl_xor(acc.w, 16);
    acc.x += __shfl_xor(acc.x, 32); acc.y += __shfl_xor(acc.y, 32);
    acc.z += __shfl_xor(acc.z, 32); acc.w += __shfl_xor(acc.w, 32);

    if (es == 0) {
        float inv = (s > 0.f) ? 1.f / s : 0.f;
        float4 b4 = ((const float4*)bias)[fg];
        float4 o;
        o.x = fmaxf(acc.x * inv + b4.x, 0.f);
        o.y = fmaxf(acc.y * inv + b4.y, 0.f);
        o.z = fmaxf(acc.z * inv + b4.z, 0.f);
        o.w = fmaxf(acc.w * inv + b4.w, 0.f);
        float4* hp = (float4*)&h[v * DD + 4 * fg];
        float4 cur = *hp;
        cur.x += o.x; cur.y += o.y; cur.z += o.z; cur.w += o.w;
        *hp = cur;
    }
}

// ---------------------------------------------------------------------------
extern "C" void kernel_launch(void* const* d_in, const int* in_sizes, int n_in,
                              void* d_out, int out_size, void* d_ws, size_t ws_size,
                              hipStream_t stream)
{
    const float* x  = (const float*)d_in[0];
    const int*   ei = (const int*)d_in[1];
    const float* W0 = (const float*)d_in[4];
    const float* b0 = (const float*)d_in[5];
    const float* W1 = (const float*)d_in[6];
    const float* as1= (const float*)d_in[7];
    const float* ad1= (const float*)d_in[8];
    const float* b1 = (const float*)d_in[9];
    const float* W2 = (const float*)d_in[10];
    const float* as2= (const float*)d_in[11];
    const float* ad2= (const float*)d_in[12];
    const float* b2 = (const float*)d_in[13];

    int N = in_sizes[0] / DD;
    int E = in_sizes[1] / 2;
    int E4 = E >> 2;
    int C4 = (E4 + NBLK - 1) / NBLK;
    int NB = (N + BN - 1) >> BSH;
    float* h = (float*)d_out;

    ushort4* hxb4 = (ushort4*)d_ws;                      // N*16 ushort4 (6.4 MB)
    float* sarr   = (float*)(hxb4 + (size_t)N * 16);     // N
    float* darr   = sarr + N;                            // N
    int*   row_ptr= (int*)(darr + N);                    // N+1
    int*   cnts   = row_ptr + (N + 1);                   // NBLK*NB
    int*   cbase  = cnts + NBLK * NB;                    // NBLK*NB
    int*   boff   = cbase + NBLK * NB;                   // NB+1
    int*   ebuf   = boff + (NB + 1);                     // E
    int*   colb   = ebuf + E;                            // E

    const int* src = ei;
    const int* dst = ei + E;
    const int4* dst4 = (const int4*)dst;
    const int4* src4 = (const int4*)src;

    int mm_tiles = (N + 63) / 64;
    int agg_blks = (N + 3) / 4;

    // ---- CSR build: privatized multi-split (no global atomics) ----
    chunk_count<<<NBLK, 512, 0, stream>>>(dst4, dst, cnts, NB, E4, E, C4);
    csr_scan<<<1, 256, 0, stream>>>(cnts, boff, cbase, row_ptr, NB, N, E);
    chunk_scatter<<<NBLK, 512, 0, stream>>>(dst4, src4, dst, src, cbase, ebuf, NB, E4, E, C4);
    group_build<<<NB, 512, 0, stream>>>(ebuf, boff, row_ptr, colb, N);

    // ---- layer 0 + GAT-1 matmul (fused) ----
    mm_fused<<<mm_tiles, 256, 0, stream>>>(x, W0, b0, W1, as1, ad1, h, hxb4, sarr, darr, N);
    aggregate<<<agg_blks, 256, 0, stream>>>(hxb4, row_ptr, colb, sarr, darr, b1, h, N);

    // ---- GAT layer 2 ----
    mm_gat<<<mm_tiles, 256, 0, stream>>>(h, W2, as2, ad2, hxb4, sarr, darr, N);
    aggregate<<<agg_blks, 256, 0, stream>>>(hxb4, row_ptr, colb, sarr, darr, b2, h, N);
}